// Round 1
// 1379.042 us; speedup vs baseline: 1.2915x; 1.2915x over previous
//
#include <hip/hip_runtime.h>
#include <hip/hip_bf16.h>

// Problem constants
#define B_   2
#define S_   2048
#define DIM_ 4096
#define H_   32
#define KV_  8
#define HD_  128
#define MROWS_ (B_ * S_)   // 4096
#define KVD_ (KV_ * HD_)   // 1024

typedef __attribute__((ext_vector_type(8))) short short8;
typedef __attribute__((ext_vector_type(4))) float floatx4;

__device__ __forceinline__ float bf2f(unsigned short u) {
    union { unsigned int i; float f; } v; v.i = ((unsigned int)u) << 16; return v.f;
}

// fp32 -> bf16 bits, round-to-nearest-even (inputs are finite; no NaN path)
__device__ __forceinline__ unsigned int f2bf(float f) {
    union { float f; unsigned int u; } v; v.f = f;
    unsigned int lsb = (v.u >> 16) & 1u;
    v.u += 0x7fffu + lsb;
    return v.u >> 16;
}
__device__ __forceinline__ unsigned int pack2bf(float lo, float hi) {
    return f2bf(lo) | (f2bf(hi) << 16);
}

// Load 8 contiguous fp32, convert to bf16 bits packed in a uint4.
__device__ __forceinline__ uint4 load8cvt(const float* __restrict__ src) {
    const float4 a = ((const float4*)src)[0];
    const float4 b = ((const float4*)src)[1];
    uint4 r;
    r.x = pack2bf(a.x, a.y);
    r.y = pack2bf(a.z, a.w);
    r.z = pack2bf(b.x, b.y);
    r.w = pack2bf(b.z, b.w);
    return r;
}

__device__ __forceinline__ void storeC(float* p, float v) { *p = v; }
__device__ __forceinline__ void storeC(__hip_bfloat16* p, float v) { *p = __float2bfloat16(v); }

// Async global->LDS, 16B per lane. LDS dest is wave-uniform base + lane*16.
__device__ __forceinline__ void gload16(const unsigned short* g, unsigned short* l)
{
    __builtin_amdgcn_global_load_lds(
        (const __attribute__((address_space(1))) void*)g,
        (__attribute__((address_space(3))) void*)l,
        16, 0, 0);
}

// ---------------------------------------------------------------------------
// x fp32 -> bf16 (row-major copy-convert), 8 elems/thread
// ---------------------------------------------------------------------------
__global__ __launch_bounds__(256)
void convert_bf16(const float* __restrict__ X, unsigned short* __restrict__ Y, int total8)
{
    const int i = blockIdx.x * 256 + threadIdx.x;
    if (i >= total8) return;
    uint4 v = load8cvt(X + (size_t)i * 8);
    *(uint4*)(Y + (size_t)i * 8) = v;
}

// ---------------------------------------------------------------------------
// Weight transpose+convert: W fp32 [K,N] -> Wt bf16 [N,K]. 64x64 LDS tile.
// ---------------------------------------------------------------------------
__global__ __launch_bounds__(256)
void wtrans(const float* __restrict__ W, unsigned short* __restrict__ Wt, int K, int N)
{
    __shared__ float tile[64][65];
    const int n0 = blockIdx.x * 64;
    const int k0 = blockIdx.y * 64;
    const int t  = threadIdx.x;
    #pragma unroll
    for (int it = 0; it < 4; ++it) {
        const int seg = t + it * 256;          // 0..1023
        const int r   = seg >> 4;              // 0..63 (k)
        const int c   = (seg & 15) << 2;       // 0..60 (n)
        const float4 v = *(const float4*)&W[(size_t)(k0 + r) * N + n0 + c];
        tile[r][c]     = v.x;
        tile[r][c + 1] = v.y;
        tile[r][c + 2] = v.z;
        tile[r][c + 3] = v.w;
    }
    __syncthreads();
    const int n  = t >> 2;                     // 0..63
    const int ks = (t & 3) << 4;               // 0,16,32,48
    unsigned int ob[8];
    #pragma unroll
    for (int j = 0; j < 8; ++j)
        ob[j] = pack2bf(tile[ks + 2 * j][n], tile[ks + 2 * j + 1][n]);
    uint4* dst = (uint4*)&Wt[(size_t)(n0 + n) * K + k0 + ks];
    dst[0] = ((const uint4*)ob)[0];
    dst[1] = ((const uint4*)ob)[1];
}

// ---------------------------------------------------------------------------
// GEMM (m97 structure): C[M,N] = A[M,K] @ Bt[N,K]^T, both bf16.
// 128x128 tile, BK=32, 4 waves x (64x64), global_load_lds width-16 staging
// into linear LDS, both fragments k-contiguous ds_read_b128.
// ---------------------------------------------------------------------------
template <typename TC>
__global__ __launch_bounds__(256)
void gemm_bt(const unsigned short* __restrict__ A,   // [M,K] bf16
             const unsigned short* __restrict__ Bt,  // [N,K] bf16
             TC* __restrict__ C,
             int M, int N, int K)
{
    __shared__ unsigned short As[128 * 32];   // linear [row][k], no pad (gload_lds)
    __shared__ unsigned short Bs[128 * 32];   // linear [n][k]

    const int tid  = threadIdx.x;
    const int lane = tid & 63;
    const int w    = tid >> 6;
    const int wm   = (w >> 1) * 64;
    const int wn   = (w & 1) * 64;
    const int m0   = blockIdx.y * 128;
    const int n0   = blockIdx.x * 128;
    const int fm   = lane & 15;
    const int fk   = (lane >> 4) * 8;

    floatx4 acc[4][4] = {};

    // staging: thread t covers flat shorts [t*8, t*8+8) (+2048 for 2nd issue)
    const int sr = tid >> 2;              // 0..63
    const int sk = (tid & 3) * 8;         // 0,8,16,24
    const unsigned short* ga0 = A  + (size_t)(m0 + sr) * K + sk;
    const unsigned short* ga1 = ga0 + (size_t)64 * K;
    const unsigned short* gb0 = Bt + (size_t)(n0 + sr) * K + sk;
    const unsigned short* gb1 = gb0 + (size_t)64 * K;
    unsigned short* lA = As + w * 512;    // wave-uniform LDS base (lane*16B added by HW)
    unsigned short* lB = Bs + w * 512;

    for (int k0 = 0; k0 < K; k0 += 32) {
        gload16(ga0 + k0, lA);
        gload16(ga1 + k0, lA + 2048);
        gload16(gb0 + k0, lB);
        gload16(gb1 + k0, lB + 2048);
        __syncthreads();   // drains vmcnt(0): tile resident

        short8 af[4], bf[4];
        #pragma unroll
        for (int i = 0; i < 4; ++i) {
            af[i] = *(const short8*)&As[(wm + i * 16 + fm) * 32 + fk];
            bf[i] = *(const short8*)&Bs[(wn + i * 16 + fm) * 32 + fk];
        }
        #pragma unroll
        for (int mi = 0; mi < 4; ++mi)
            #pragma unroll
            for (int ni = 0; ni < 4; ++ni)
                acc[mi][ni] = __builtin_amdgcn_mfma_f32_16x16x32_bf16(
                    af[mi], bf[ni], acc[mi][ni], 0, 0, 0);
        __syncthreads();   // all reads done before next iter's async LDS writes
    }

    const int cl = lane & 15;
    const int rq = (lane >> 4) * 4;
    #pragma unroll
    for (int mi = 0; mi < 4; ++mi) {
        #pragma unroll
        for (int ni = 0; ni < 4; ++ni) {
            const int col = n0 + wn + ni * 16 + cl;
            #pragma unroll
            for (int r = 0; r < 4; ++r) {
                const int row = m0 + wm + mi * 16 + rq + r;
                storeC(C + (size_t)row * N + col, acc[mi][ni][r]);
            }
        }
    }
}

// ---------------------------------------------------------------------------
// RoPE in-place on T (bf16): [B*S, NH, 128]. cos/sin are fp32 [S,1,128].
// ---------------------------------------------------------------------------
__global__ void rope_kernel(__hip_bfloat16* __restrict__ T,
                            const float* __restrict__ cosb,
                            const float* __restrict__ sinb,
                            int NH, int total)
{
    int idx = blockIdx.x * blockDim.x + threadIdx.x;
    if (idx >= total) return;
    const int dh   = idx & 63;
    const int rest = idx >> 6;
    const int h    = rest % NH;
    const int bs   = rest / NH;       // b*S + s
    const int s    = bs & (S_ - 1);
    const size_t base = ((size_t)bs * NH + h) * HD_;
    const float t1 = __bfloat162float(T[base + dh]);
    const float t2 = __bfloat162float(T[base + dh + 64]);
    const float c1 = cosb[s * HD_ + dh];
    const float s1 = sinb[s * HD_ + dh];
    const float c2 = cosb[s * HD_ + dh + 64];
    const float s2 = sinb[s * HD_ + dh + 64];
    T[base + dh]      = __float2bfloat16(t1 * c1 - t2 * s1);
    T[base + dh + 64] = __float2bfloat16(t2 * c2 + t1 * s2);
}

// ---------------------------------------------------------------------------
// MFMA flash attention. Block = (b,h) x 128-row Q tile; 4 waves x 32 q-rows.
// This round: (1) qt reversed so heavy causal tiles dispatch first;
// (2) K/V global loads prefetched into registers one tile ahead (T14);
// (3) Vt write swizzle col^=(d>>5)<<4 (8-way -> conflict-free scatter);
// (4) Ps store swizzle col^=(row>>2&3)<<3 (4-way -> conflict-free).
// ---------------------------------------------------------------------------
#define LOG2E 1.4426950408889634f

__global__ __launch_bounds__(256, 3)
void attn_mfma(const __hip_bfloat16* __restrict__ Q,
               const __hip_bfloat16* __restrict__ K,
               const __hip_bfloat16* __restrict__ V,
               __hip_bfloat16* __restrict__ O)
{
    const int qt = (int)gridDim.x - 1 - (int)blockIdx.x;   // heavy tiles first
    const int bh = blockIdx.y;          // 0..63
    const int b  = bh >> 5;
    const int h  = bh & 31;
    const int g  = h >> 2;              // kv head
    const int q0 = qt * 128;

    __shared__ unsigned short Ks[64][136];    // K tile, key-major (+8 pad)
    __shared__ unsigned short Vt[128][72];    // V transposed: [d][key ^ ((d>>5)<<4)]
    __shared__ unsigned short Ps[4][32][72];  // per-wave P, col ^ ((row>>2&3)<<3)

    const int tid  = threadIdx.x;
    const int lane = tid & 63;
    const int w    = tid >> 6;
    const int fm   = lane & 15;
    const int quad = lane >> 4;
    const int fk   = quad * 8;

    const int qrow_base = q0 + w * 32;

    // Q A-fragments: [mt][dt], resident for whole kernel
    short8 qf[2][4];
    #pragma unroll
    for (int mt = 0; mt < 2; ++mt) {
        const int row = qrow_base + mt * 16 + fm;
        const __hip_bfloat16* qp = Q + ((size_t)(b * S_ + row) * H_ + h) * HD_;
        #pragma unroll
        for (int dt = 0; dt < 4; ++dt)
            qf[mt][dt] = *(const short8*)(qp + dt * 32 + fk);
    }

    floatx4 o_acc[2][8] = {};
    float m_r[2][4], l_r[2][4];
    #pragma unroll
    for (int mt = 0; mt < 2; ++mt)
        #pragma unroll
        for (int r = 0; r < 4; ++r) { m_r[mt][r] = -1e30f; l_r[mt][r] = 0.f; }

    const float scale = 0.08838834764831845f;   // 1/sqrt(128)

    // staging geometry + register prefetch (issue-early / write-late)
    const int key  = tid >> 2;                   // 0..63
    const int d0   = (tid & 3) * 32;
    const int vcol = key ^ ((tid & 3) << 4);     // Vt write swizzle: (d>>5)==tid&3
    const unsigned short* Kp = (const unsigned short*)K;
    const unsigned short* Vp = (const unsigned short*)V;
    const size_t gbase = ((size_t)(b * S_ + key) * KV_ + g) * HD_ + d0;
    const size_t gstep = (size_t)64 * KV_ * HD_;
    uint4 kreg[4], vreg[4];

    auto stage_load = [&](int kt) {
        const uint4* kp = (const uint4*)(Kp + gbase + (size_t)kt * gstep);
        const uint4* vp = (const uint4*)(Vp + gbase + (size_t)kt * gstep);
        kreg[0] = kp[0]; kreg[1] = kp[1]; kreg[2] = kp[2]; kreg[3] = kp[3];
        vreg[0] = vp[0]; vreg[1] = vp[1]; vreg[2] = vp[2]; vreg[3] = vp[3];
    };

    const int ktiles = 2 * (qt + 1);
    stage_load(0);
    for (int kt = 0; kt < ktiles; ++kt) {
        const int k0 = kt * 64;
        __syncthreads();   // prior iter's Ks/Vt reads complete
        {   // write prefetched K (row-major) and V (transposed, swizzled cols)
            *(uint4*)&Ks[key][d0]      = kreg[0];
            *(uint4*)&Ks[key][d0 + 8]  = kreg[1];
            *(uint4*)&Ks[key][d0 + 16] = kreg[2];
            *(uint4*)&Ks[key][d0 + 24] = kreg[3];
            const unsigned short* vs = (const unsigned short*)vreg;
            #pragma unroll
            for (int i = 0; i < 32; ++i)
                Vt[d0 + i][vcol] = vs[i];
        }
        __syncthreads();
        if (kt + 1 < ktiles) stage_load(kt + 1);   // hide HBM latency under compute

        // ---- QK^T ----
        floatx4 s_acc[2][4] = {};
        #pragma unroll
        for (int dt = 0; dt < 4; ++dt) {
            #pragma unroll
            for (int nt = 0; nt < 4; ++nt) {
                short8 bfr = *(const short8*)&Ks[nt * 16 + fm][dt * 32 + fk];
                #pragma unroll
                for (int mt = 0; mt < 2; ++mt)
                    s_acc[mt][nt] = __builtin_amdgcn_mfma_f32_16x16x32_bf16(
                        qf[mt][dt], bfr, s_acc[mt][nt], 0, 0, 0);
            }
        }

        // ---- mask + online softmax (per 16-lane quad) ----
        #pragma unroll
        for (int mt = 0; mt < 2; ++mt) {
            const int rowq0 = qrow_base + mt * 16 + quad * 4;
            #pragma unroll
            for (int r = 0; r < 4; ++r) {
                const int rowq = rowq0 + r;
                float mx = -1e30f;
                #pragma unroll
                for (int nt = 0; nt < 4; ++nt) {
                    const int c = k0 + nt * 16 + fm;
                    float s = s_acc[mt][nt][r] * scale;
                    s = (c <= rowq) ? s : -1e30f;
                    s_acc[mt][nt][r] = s;
                    mx = fmaxf(mx, s);
                }
                #pragma unroll
                for (int off = 1; off < 16; off <<= 1)
                    mx = fmaxf(mx, __shfl_xor(mx, off));
                const float mold = m_r[mt][r];
                const float mnew = fmaxf(mold, mx);
                const float alpha = __expf(mold - mnew);
                float rsum = 0.f;
                #pragma unroll
                for (int nt = 0; nt < 4; ++nt) {
                    const float p = __expf(s_acc[mt][nt][r] - mnew);
                    s_acc[mt][nt][r] = p;
                    rsum += p;
                }
                #pragma unroll
                for (int off = 1; off < 16; off <<= 1)
                    rsum += __shfl_xor(rsum, off);
                m_r[mt][r] = mnew;
                l_r[mt][r] = l_r[mt][r] * alpha + rsum;
                #pragma unroll
                for (int nt = 0; nt < 8; ++nt)
                    o_acc[mt][nt][r] *= alpha;
                // store P row to per-wave LDS (bf16), swizzled: col ^ (quad<<3)
                #pragma unroll
                for (int nt = 0; nt < 4; ++nt)
                    Ps[w][mt * 16 + quad * 4 + r][(nt * 16 + fm) ^ (quad << 3)] =
                        (unsigned short)f2bf(s_acc[mt][nt][r]);
            }
        }

        // ---- PV ----
        #pragma unroll
        for (int ct = 0; ct < 2; ++ct) {
            short8 af[2];
            #pragma unroll
            for (int mt = 0; mt < 2; ++mt)
                af[mt] = *(const short8*)
                    &Ps[w][mt * 16 + fm][ct * 32 + ((quad ^ (fm >> 2)) << 3)];
            #pragma unroll
            for (int nt = 0; nt < 8; ++nt) {
                short8 bfr = *(const short8*)
                    &Vt[nt * 16 + fm][(ct * 32 + fk) ^ ((nt >> 1) << 4)];
                #pragma unroll
                for (int mt = 0; mt < 2; ++mt)
                    o_acc[mt][nt] = __builtin_amdgcn_mfma_f32_16x16x32_bf16(
                        af[mt], bfr, o_acc[mt][nt], 0, 0, 0);
            }
        }
    }

    // ---- epilogue: normalize by l, store bf16 ----
    #pragma unroll
    for (int mt = 0; mt < 2; ++mt) {
        #pragma unroll
        for (int r = 0; r < 4; ++r) {
            const int row = qrow_base + mt * 16 + quad * 4 + r;
            const float inv_l = 1.f / l_r[mt][r];
            __hip_bfloat16* op = O + ((size_t)(b * S_ + row) * H_ + h) * HD_;
            #pragma unroll
            for (int nt = 0; nt < 8; ++nt)
                op[nt * 16 + fm] = __float2bfloat16(o_acc[mt][nt][r] * inv_l);
        }
    }
}

// ---------------------------------------------------------------------------
extern "C" void kernel_launch(void* const* d_in, const int* in_sizes, int n_in,
                              void* d_out, int out_size, void* d_ws, size_t ws_size,
                              hipStream_t stream)
{
    const float* x    = (const float*)d_in[0];
    const float* cosb = (const float*)d_in[1];
    const float* sinb = (const float*)d_in[2];
    const float* Wq   = (const float*)d_in[3];
    const float* Wk   = (const float*)d_in[4];
    const float* Wv   = (const float*)d_in[5];
    const float* Wo   = (const float*)d_in[6];
    float* out = (float*)d_out;

    // Workspace layout (128 MB, slots reused along the stream timeline):
    //  [0,32)   Xb (x bf16)        -> dead after QKV projs -> WoT
    //  [32,64)  WqT                -> dead after Q proj    -> Ab (attn out)
    //  [64,72)  WkT   [72,80) WvT
    //  [80,112) Qb    [112,120) Kb   [120,128) Vb
    char* ws = (char*)d_ws;
    const size_t MB = 1024 * 1024;
    unsigned short* Xb  = (unsigned short*)(ws);
    unsigned short* WoT = (unsigned short*)(ws);
    unsigned short* WqT = (unsigned short*)(ws + 32 * MB);
    unsigned short* Ab  = (unsigned short*)(ws + 32 * MB);
    unsigned short* WkT = (unsigned short*)(ws + 64 * MB);
    unsigned short* WvT = (unsigned short*)(ws + 72 * MB);
    unsigned short* Qb  = (unsigned short*)(ws + 80 * MB);
    unsigned short* Kb  = (unsigned short*)(ws + 112 * MB);
    unsigned short* Vb  = (unsigned short*)(ws + 120 * MB);

    dim3 blk(256);

    // 1. x -> bf16 (shared A operand for Q/K/V projections)
    convert_bf16<<<dim3((MROWS_ * DIM_) / 8 / 256), blk, 0, stream>>>(
        x, Xb, (MROWS_ * DIM_) / 8);

    // 2. weight transpose+convert: [K,N] fp32 -> [N,K] bf16
    wtrans<<<dim3(DIM_ / 64, DIM_ / 64), blk, 0, stream>>>(Wq, WqT, DIM_, DIM_);
    wtrans<<<dim3(KVD_ / 64, DIM_ / 64), blk, 0, stream>>>(Wk, WkT, DIM_, KVD_);
    wtrans<<<dim3(KVD_ / 64, DIM_ / 64), blk, 0, stream>>>(Wv, WvT, DIM_, KVD_);

    // 3. projections (bf16 x bf16 -> bf16)
    gemm_bt<__hip_bfloat16><<<dim3(DIM_ / 128, MROWS_ / 128), blk, 0, stream>>>(
        Xb, WqT, (__hip_bfloat16*)Qb, MROWS_, DIM_, DIM_);
    gemm_bt<__hip_bfloat16><<<dim3(KVD_ / 128, MROWS_ / 128), blk, 0, stream>>>(
        Xb, WkT, (__hip_bfloat16*)Kb, MROWS_, KVD_, DIM_);
    gemm_bt<__hip_bfloat16><<<dim3(KVD_ / 128, MROWS_ / 128), blk, 0, stream>>>(
        Xb, WvT, (__hip_bfloat16*)Vb, MROWS_, KVD_, DIM_);

    // 4. Wo transpose into Xb's slot (Xb dead now; stream-ordered)
    wtrans<<<dim3(DIM_ / 64, DIM_ / 64), blk, 0, stream>>>(Wo, WoT, DIM_, DIM_);

    // 5. RoPE (in-place, bf16 tensors, fp32 tables)
    {
        int totq = MROWS_ * H_ * 64;
        int totk = MROWS_ * KV_ * 64;
        rope_kernel<<<(totq + 255) / 256, blk, 0, stream>>>(
            (__hip_bfloat16*)Qb, cosb, sinb, H_, totq);
        rope_kernel<<<(totk + 255) / 256, blk, 0, stream>>>(
            (__hip_bfloat16*)Kb, cosb, sinb, KV_, totk);
    }

    // 6. MFMA flash attention -> Ab (WqT slot)
    attn_mfma<<<dim3(S_ / 128, B_ * H_), blk, 0, stream>>>(
        (const __hip_bfloat16*)Qb, (const __hip_bfloat16*)Kb,
        (const __hip_bfloat16*)Vb, (__hip_bfloat16*)Ab);

    // 7. output projection: Ab bf16 @ WoT -> fp32 out
    gemm_bt<float><<<dim3(DIM_ / 128, MROWS_ / 128), blk, 0, stream>>>(
        Ab, WoT, out, MROWS_, DIM_, DIM_);
}

// Round 2
// 1104.143 us; speedup vs baseline: 1.6130x; 1.2490x over previous
//
#include <hip/hip_runtime.h>
#include <hip/hip_bf16.h>

// Problem constants
#define B_   2
#define S_   2048
#define DIM_ 4096
#define H_   32
#define KV_  8
#define HD_  128
#define MROWS_ (B_ * S_)   // 4096
#define KVD_ (KV_ * HD_)   // 1024
#define QKVN_ (DIM_ + 2 * KVD_)   // 6144, fused QKV row stride

typedef __attribute__((ext_vector_type(8))) short short8;
typedef __attribute__((ext_vector_type(4))) float floatx4;

// fp32 -> bf16 bits, round-to-nearest-even (inputs are finite; no NaN path)
__device__ __forceinline__ unsigned int f2bf(float f) {
    union { float f; unsigned int u; } v; v.f = f;
    unsigned int lsb = (v.u >> 16) & 1u;
    v.u += 0x7fffu + lsb;
    return v.u >> 16;
}
__device__ __forceinline__ unsigned int pack2bf(float lo, float hi) {
    return f2bf(lo) | (f2bf(hi) << 16);
}

// Load 8 contiguous fp32, convert to bf16 bits packed in a uint4.
__device__ __forceinline__ uint4 load8cvt(const float* __restrict__ src) {
    const float4 a = ((const float4*)src)[0];
    const float4 b = ((const float4*)src)[1];
    uint4 r;
    r.x = pack2bf(a.x, a.y);
    r.y = pack2bf(a.z, a.w);
    r.z = pack2bf(b.x, b.y);
    r.w = pack2bf(b.z, b.w);
    return r;
}

__device__ __forceinline__ void storeC(float* p, float v) { *p = v; }
__device__ __forceinline__ void storeC(__hip_bfloat16* p, float v) { *p = __float2bfloat16(v); }

// Async global->LDS, 16B per lane. LDS dest is wave-uniform base + lane*16.
__device__ __forceinline__ void gload16(const unsigned short* g, unsigned short* l)
{
    __builtin_amdgcn_global_load_lds(
        (const __attribute__((address_space(1))) void*)g,
        (__attribute__((address_space(3))) void*)l,
        16, 0, 0);
}

// ---------------------------------------------------------------------------
// x fp32 -> bf16 (row-major copy-convert), 8 elems/thread
// ---------------------------------------------------------------------------
__global__ __launch_bounds__(256)
void convert_bf16(const float* __restrict__ X, unsigned short* __restrict__ Y, int total8)
{
    const int i = blockIdx.x * 256 + threadIdx.x;
    if (i >= total8) return;
    uint4 v = load8cvt(X + (size_t)i * 8);
    *(uint4*)(Y + (size_t)i * 8) = v;
}

// ---------------------------------------------------------------------------
// Weight transpose+convert: W fp32 [K,N] -> Wt bf16 [N,K]. 64x64 LDS tile.
// ---------------------------------------------------------------------------
__global__ __launch_bounds__(256)
void wtrans(const float* __restrict__ W, unsigned short* __restrict__ Wt, int K, int N)
{
    __shared__ float tile[64][65];
    const int n0 = blockIdx.x * 64;
    const int k0 = blockIdx.y * 64;
    const int t  = threadIdx.x;
    #pragma unroll
    for (int it = 0; it < 4; ++it) {
        const int seg = t + it * 256;          // 0..1023
        const int r   = seg >> 4;              // 0..63 (k)
        const int c   = (seg & 15) << 2;       // 0..60 (n)
        const float4 v = *(const float4*)&W[(size_t)(k0 + r) * N + n0 + c];
        tile[r][c]     = v.x;
        tile[r][c + 1] = v.y;
        tile[r][c + 2] = v.z;
        tile[r][c + 3] = v.w;
    }
    __syncthreads();
    const int n  = t >> 2;                     // 0..63
    const int ks = (t & 3) << 4;               // 0,16,32,48
    unsigned int ob[8];
    #pragma unroll
    for (int j = 0; j < 8; ++j)
        ob[j] = pack2bf(tile[ks + 2 * j][n], tile[ks + 2 * j + 1][n]);
    uint4* dst = (uint4*)&Wt[(size_t)(n0 + n) * K + k0 + ks];
    dst[0] = ((const uint4*)ob)[0];
    dst[1] = ((const uint4*)ob)[1];
}

// ---------------------------------------------------------------------------
// GEMM (m97 structure): C[M,N] = A[M,K] @ Bt[N,K]^T, both bf16.
// 128x128 tile, BK=32, 4 waves x (64x64), global_load_lds width-16 staging
// into linear LDS, both fragments k-contiguous ds_read_b128.
// XCD-aware bijective block swizzle (T1) when nwg % 8 == 0.
// ---------------------------------------------------------------------------
template <typename TC>
__global__ __launch_bounds__(256)
void gemm_bt(const unsigned short* __restrict__ A,   // [M,K] bf16
             const unsigned short* __restrict__ Bt,  // [N,K] bf16
             TC* __restrict__ C,
             int M, int N, int K)
{
    __shared__ unsigned short As[128 * 32];   // linear [row][k], no pad (gload_lds)
    __shared__ unsigned short Bs[128 * 32];   // linear [n][k]

    const int tid  = threadIdx.x;
    const int lane = tid & 63;
    const int w    = tid >> 6;
    const int wm   = (w >> 1) * 64;
    const int wn   = (w & 1) * 64;

    const int gx  = gridDim.x;
    const int nwg = gx * gridDim.y;
    int lid = blockIdx.y * gx + blockIdx.x;
    if ((nwg & 7) == 0) {                     // contiguous chunk per XCD
        const int q = nwg >> 3;
        lid = (lid & 7) * q + (lid >> 3);
    }
    const int m0 = (lid / gx) * 128;
    const int n0 = (lid % gx) * 128;

    const int fm   = lane & 15;
    const int fk   = (lane >> 4) * 8;

    floatx4 acc[4][4] = {};

    // staging: thread t covers flat shorts [t*8, t*8+8) (+2048 for 2nd issue)
    const int sr = tid >> 2;              // 0..63
    const int sk = (tid & 3) * 8;         // 0,8,16,24
    const unsigned short* ga0 = A  + (size_t)(m0 + sr) * K + sk;
    const unsigned short* ga1 = ga0 + (size_t)64 * K;
    const unsigned short* gb0 = Bt + (size_t)(n0 + sr) * K + sk;
    const unsigned short* gb1 = gb0 + (size_t)64 * K;
    unsigned short* lA = As + w * 512;    // wave-uniform LDS base (lane*16B added by HW)
    unsigned short* lB = Bs + w * 512;

    for (int k0 = 0; k0 < K; k0 += 32) {
        gload16(ga0 + k0, lA);
        gload16(ga1 + k0, lA + 2048);
        gload16(gb0 + k0, lB);
        gload16(gb1 + k0, lB + 2048);
        __syncthreads();   // drains vmcnt(0): tile resident

        short8 af[4], bf[4];
        #pragma unroll
        for (int i = 0; i < 4; ++i) {
            af[i] = *(const short8*)&As[(wm + i * 16 + fm) * 32 + fk];
            bf[i] = *(const short8*)&Bs[(wn + i * 16 + fm) * 32 + fk];
        }
        #pragma unroll
        for (int mi = 0; mi < 4; ++mi)
            #pragma unroll
            for (int ni = 0; ni < 4; ++ni)
                acc[mi][ni] = __builtin_amdgcn_mfma_f32_16x16x32_bf16(
                    af[mi], bf[ni], acc[mi][ni], 0, 0, 0);
        __syncthreads();   // all reads done before next iter's async LDS writes
    }

    const int cl = lane & 15;
    const int rq = (lane >> 4) * 4;
    #pragma unroll
    for (int mi = 0; mi < 4; ++mi) {
        #pragma unroll
        for (int ni = 0; ni < 4; ++ni) {
            const int col = n0 + wn + ni * 16 + cl;
            #pragma unroll
            for (int r = 0; r < 4; ++r) {
                const int row = m0 + wm + mi * 16 + rq + r;
                storeC(C + (size_t)row * N + col, acc[mi][ni][r]);
            }
        }
    }
}

// ---------------------------------------------------------------------------
// RoPE in-place on fused QKV (bf16): row bs, columns [coloff + h*128 .. ).
// cos/sin are fp32 [S,1,128].
// ---------------------------------------------------------------------------
__global__ void rope_kernel(unsigned short* __restrict__ T,
                            const float* __restrict__ cosb,
                            const float* __restrict__ sinb,
                            int NH, int coloff, int total)
{
    int idx = blockIdx.x * blockDim.x + threadIdx.x;
    if (idx >= total) return;
    const int dh   = idx & 63;
    const int rest = idx >> 6;
    const int h    = rest % NH;
    const int bs   = rest / NH;       // b*S + s
    const int s    = bs & (S_ - 1);
    const size_t base = (size_t)bs * QKVN_ + coloff + h * HD_;
    union { unsigned short u; __hip_bfloat16 b; } c1v, c2v;
    const float t1 = __bfloat162float(*(__hip_bfloat16*)&T[base + dh]);
    const float t2 = __bfloat162float(*(__hip_bfloat16*)&T[base + dh + 64]);
    const float c1 = cosb[s * HD_ + dh];
    const float s1 = sinb[s * HD_ + dh];
    const float c2 = cosb[s * HD_ + dh + 64];
    const float s2 = sinb[s * HD_ + dh + 64];
    T[base + dh]      = (unsigned short)f2bf(t1 * c1 - t2 * s1);
    T[base + dh + 64] = (unsigned short)f2bf(t2 * c2 + t1 * s2);
    (void)c1v; (void)c2v;
}

// ---------------------------------------------------------------------------
// MFMA flash attention on fused QKV layout (row stride 6144).
// Block = (b,h) x 128-row Q tile; 4 waves x 32 q-rows. qt reversed so heavy
// causal tiles dispatch first. K/V register-prefetched one tile ahead (T14);
// NO launch-bounds min-waves cap (round-1's cap caused scratch spill).
// Vt write swizzle col^=(d>>5)<<4; Ps store swizzle col^=(row>>2&3)<<3.
// ---------------------------------------------------------------------------
__global__ __launch_bounds__(256)
void attn_mfma(const unsigned short* __restrict__ QKV,
               __hip_bfloat16* __restrict__ O)
{
    const int qt = (int)gridDim.x - 1 - (int)blockIdx.x;   // heavy tiles first
    const int bh = blockIdx.y;          // 0..63
    const int b  = bh >> 5;
    const int h  = bh & 31;
    const int g  = h >> 2;              // kv head
    const int q0 = qt * 128;

    __shared__ unsigned short Ks[64][136];    // K tile, key-major (+8 pad)
    __shared__ unsigned short Vt[128][72];    // V transposed: [d][key ^ ((d>>5)<<4)]
    __shared__ unsigned short Ps[4][32][72];  // per-wave P, col ^ ((row>>2&3)<<3)

    const int tid  = threadIdx.x;
    const int lane = tid & 63;
    const int w    = tid >> 6;
    const int fm   = lane & 15;
    const int quad = lane >> 4;
    const int fk   = quad * 8;

    const int qrow_base = q0 + w * 32;

    // Q A-fragments: [mt][dt], resident for whole kernel
    short8 qf[2][4];
    #pragma unroll
    for (int mt = 0; mt < 2; ++mt) {
        const int row = qrow_base + mt * 16 + fm;
        const unsigned short* qp = QKV + (size_t)(b * S_ + row) * QKVN_ + h * HD_;
        #pragma unroll
        for (int dt = 0; dt < 4; ++dt)
            qf[mt][dt] = *(const short8*)(qp + dt * 32 + fk);
    }

    floatx4 o_acc[2][8] = {};
    float m_r[2][4], l_r[2][4];
    #pragma unroll
    for (int mt = 0; mt < 2; ++mt)
        #pragma unroll
        for (int r = 0; r < 4; ++r) { m_r[mt][r] = -1e30f; l_r[mt][r] = 0.f; }

    const float scale = 0.08838834764831845f;   // 1/sqrt(128)

    // staging geometry + register prefetch (issue-early / write-late)
    const int key  = tid >> 2;                   // 0..63
    const int d0   = (tid & 3) * 32;
    const int vcol = key ^ ((tid & 3) << 4);     // Vt write swizzle: (d>>5)==tid&3
    const unsigned short* Kp = QKV + DIM_ + g * HD_;          // K section
    const unsigned short* Vp = QKV + DIM_ + KVD_ + g * HD_;   // V section
    const size_t gbase = (size_t)(b * S_ + key) * QKVN_ + d0;
    const size_t gstep = (size_t)64 * QKVN_;
    uint4 kreg[4], vreg[4];

    const int ktiles = 2 * (qt + 1);
    {
        const uint4* kp = (const uint4*)(Kp + gbase);
        const uint4* vp = (const uint4*)(Vp + gbase);
        #pragma unroll
        for (int i = 0; i < 4; ++i) { kreg[i] = kp[i]; vreg[i] = vp[i]; }
    }
    for (int kt = 0; kt < ktiles; ++kt) {
        const int k0 = kt * 64;
        __syncthreads();   // prior iter's Ks/Vt reads complete
        {   // write prefetched K (row-major) and V (transposed, swizzled cols)
            *(uint4*)&Ks[key][d0]      = kreg[0];
            *(uint4*)&Ks[key][d0 + 8]  = kreg[1];
            *(uint4*)&Ks[key][d0 + 16] = kreg[2];
            *(uint4*)&Ks[key][d0 + 24] = kreg[3];
            const unsigned short* vs = (const unsigned short*)vreg;
            #pragma unroll
            for (int i = 0; i < 32; ++i)
                Vt[d0 + i][vcol] = vs[i];
        }
        __syncthreads();
        if (kt + 1 < ktiles) {   // prefetch next tile; HBM latency hides under compute
            const uint4* kp = (const uint4*)(Kp + gbase + (size_t)(kt + 1) * gstep);
            const uint4* vp = (const uint4*)(Vp + gbase + (size_t)(kt + 1) * gstep);
            #pragma unroll
            for (int i = 0; i < 4; ++i) { kreg[i] = kp[i]; vreg[i] = vp[i]; }
        }

        // ---- QK^T ----
        floatx4 s_acc[2][4] = {};
        #pragma unroll
        for (int dt = 0; dt < 4; ++dt) {
            #pragma unroll
            for (int nt = 0; nt < 4; ++nt) {
                short8 bfr = *(const short8*)&Ks[nt * 16 + fm][dt * 32 + fk];
                #pragma unroll
                for (int mt = 0; mt < 2; ++mt)
                    s_acc[mt][nt] = __builtin_amdgcn_mfma_f32_16x16x32_bf16(
                        qf[mt][dt], bfr, s_acc[mt][nt], 0, 0, 0);
            }
        }

        // ---- mask + online softmax (per 16-lane quad) ----
        #pragma unroll
        for (int mt = 0; mt < 2; ++mt) {
            const int rowq0 = qrow_base + mt * 16 + quad * 4;
            #pragma unroll
            for (int r = 0; r < 4; ++r) {
                const int rowq = rowq0 + r;
                float mx = -1e30f;
                #pragma unroll
                for (int nt = 0; nt < 4; ++nt) {
                    const int c = k0 + nt * 16 + fm;
                    float s = s_acc[mt][nt][r] * scale;
                    s = (c <= rowq) ? s : -1e30f;
                    s_acc[mt][nt][r] = s;
                    mx = fmaxf(mx, s);
                }
                #pragma unroll
                for (int off = 1; off < 16; off <<= 1)
                    mx = fmaxf(mx, __shfl_xor(mx, off));
                const float mold = m_r[mt][r];
                const float mnew = fmaxf(mold, mx);
                const float alpha = __expf(mold - mnew);
                float rsum = 0.f;
                #pragma unroll
                for (int nt = 0; nt < 4; ++nt) {
                    const float p = __expf(s_acc[mt][nt][r] - mnew);
                    s_acc[mt][nt][r] = p;
                    rsum += p;
                }
                #pragma unroll
                for (int off = 1; off < 16; off <<= 1)
                    rsum += __shfl_xor(rsum, off);
                m_r[mt][r] = mnew;
                l_r[mt][r] = l_r[mt][r] * alpha + rsum;
                #pragma unroll
                for (int nt = 0; nt < 8; ++nt)
                    o_acc[mt][nt][r] *= alpha;
                // store P row to per-wave LDS (bf16), swizzled: col ^ (quad<<3)
                #pragma unroll
                for (int nt = 0; nt < 4; ++nt)
                    Ps[w][mt * 16 + quad * 4 + r][(nt * 16 + fm) ^ (quad << 3)] =
                        (unsigned short)f2bf(s_acc[mt][nt][r]);
            }
        }

        // ---- PV ----
        #pragma unroll
        for (int ct = 0; ct < 2; ++ct) {
            short8 af[2];
            #pragma unroll
            for (int mt = 0; mt < 2; ++mt)
                af[mt] = *(const short8*)
                    &Ps[w][mt * 16 + fm][ct * 32 + ((quad ^ (fm >> 2)) << 3)];
            #pragma unroll
            for (int nt = 0; nt < 8; ++nt) {
                short8 bfr = *(const short8*)
                    &Vt[nt * 16 + fm][(ct * 32 + fk) ^ ((nt >> 1) << 4)];
                #pragma unroll
                for (int mt = 0; mt < 2; ++mt)
                    o_acc[mt][nt] = __builtin_amdgcn_mfma_f32_16x16x32_bf16(
                        af[mt], bfr, o_acc[mt][nt], 0, 0, 0);
            }
        }
    }

    // ---- epilogue: normalize by l, store bf16 (dense [bs][4096] layout) ----
    #pragma unroll
    for (int mt = 0; mt < 2; ++mt) {
        #pragma unroll
        for (int r = 0; r < 4; ++r) {
            const int row = qrow_base + mt * 16 + quad * 4 + r;
            const float inv_l = 1.f / l_r[mt][r];
            __hip_bfloat16* op = O + ((size_t)(b * S_ + row) * H_ + h) * HD_;
            #pragma unroll
            for (int nt = 0; nt < 8; ++nt)
                op[nt * 16 + fm] = __float2bfloat16(o_acc[mt][nt][r] * inv_l);
        }
    }
}

// ---------------------------------------------------------------------------
extern "C" void kernel_launch(void* const* d_in, const int* in_sizes, int n_in,
                              void* d_out, int out_size, void* d_ws, size_t ws_size,
                              hipStream_t stream)
{
    const float* x    = (const float*)d_in[0];
    const float* cosb = (const float*)d_in[1];
    const float* sinb = (const float*)d_in[2];
    const float* Wq   = (const float*)d_in[3];
    const float* Wk   = (const float*)d_in[4];
    const float* Wv   = (const float*)d_in[5];
    const float* Wo   = (const float*)d_in[6];
    float* out = (float*)d_out;

    // Workspace layout (128 MB, slots reused along the stream timeline):
    //  [0,32)   Xb (x bf16)          -> dead after QKV gemm -> Ab (attn out)
    //  [32,80)  WT (fused WqT|WkT|WvT [6144,4096]) -> dead after QKV gemm
    //           -> WoT at [32,64)
    //  [80,128) QKV (fused [4096,6144] bf16)
    char* ws = (char*)d_ws;
    const size_t MB = 1024 * 1024;
    unsigned short* Xb  = (unsigned short*)(ws);
    unsigned short* Ab  = (unsigned short*)(ws);
    unsigned short* WT  = (unsigned short*)(ws + 32 * MB);
    unsigned short* WoT = (unsigned short*)(ws + 32 * MB);
    unsigned short* QKV = (unsigned short*)(ws + 80 * MB);

    unsigned short* WTq = WT;
    unsigned short* WTk = WT + (size_t)DIM_ * DIM_;           // rows 4096..5119
    unsigned short* WTv = WT + (size_t)(DIM_ + KVD_) * DIM_;  // rows 5120..6143

    dim3 blk(256);

    // 1. x -> bf16 (shared A operand for QKV projection)
    convert_bf16<<<dim3((MROWS_ * DIM_) / 8 / 256), blk, 0, stream>>>(
        x, Xb, (MROWS_ * DIM_) / 8);

    // 2. weight transpose+convert into fused WT: [K,N] fp32 -> [N,K] bf16
    wtrans<<<dim3(DIM_ / 64, DIM_ / 64), blk, 0, stream>>>(Wq, WTq, DIM_, DIM_);
    wtrans<<<dim3(KVD_ / 64, DIM_ / 64), blk, 0, stream>>>(Wk, WTk, DIM_, KVD_);
    wtrans<<<dim3(KVD_ / 64, DIM_ / 64), blk, 0, stream>>>(Wv, WTv, DIM_, KVD_);

    // 3. fused QKV projection: [4096,4096] @ [4096,6144] -> [4096,6144] bf16
    gemm_bt<__hip_bfloat16><<<dim3(QKVN_ / 128, MROWS_ / 128), blk, 0, stream>>>(
        Xb, WT, (__hip_bfloat16*)QKV, MROWS_, QKVN_, DIM_);

    // 4. Wo transpose into WT's (now dead) slot
    wtrans<<<dim3(DIM_ / 64, DIM_ / 64), blk, 0, stream>>>(Wo, WoT, DIM_, DIM_);

    // 5. RoPE in-place on fused QKV (Q section then K section)
    {
        int totq = MROWS_ * H_ * 64;
        int totk = MROWS_ * KV_ * 64;
        rope_kernel<<<(totq + 255) / 256, blk, 0, stream>>>(
            QKV, cosb, sinb, H_, 0, totq);
        rope_kernel<<<(totk + 255) / 256, blk, 0, stream>>>(
            QKV, cosb, sinb, KV_, DIM_, totk);
    }

    // 6. MFMA flash attention -> Ab (Xb slot, dead after QKV gemm)
    attn_mfma<<<dim3(S_ / 128, B_ * H_), blk, 0, stream>>>(
        QKV, (__hip_bfloat16*)Ab);

    // 7. output projection: Ab bf16 @ WoT -> fp32 out
    gemm_bt<float><<<dim3(DIM_ / 128, MROWS_ / 128), blk, 0, stream>>>(
        Ab, WoT, out, MROWS_, DIM_, DIM_);
}

// Round 3
// 1101.268 us; speedup vs baseline: 1.6172x; 1.0026x over previous
//
#include <hip/hip_runtime.h>
#include <hip/hip_bf16.h>

// Problem constants
#define B_   2
#define S_   2048
#define DIM_ 4096
#define H_   32
#define KV_  8
#define HD_  128
#define MROWS_ (B_ * S_)   // 4096
#define KVD_ (KV_ * HD_)   // 1024
#define QKVN_ (DIM_ + 2 * KVD_)   // 6144, fused QKV row stride

typedef __attribute__((ext_vector_type(8))) short short8;
typedef __attribute__((ext_vector_type(4))) float floatx4;

// fp32 -> bf16 bits, round-to-nearest-even (inputs are finite; no NaN path)
__device__ __forceinline__ unsigned int f2bf(float f) {
    union { float f; unsigned int u; } v; v.f = f;
    unsigned int lsb = (v.u >> 16) & 1u;
    v.u += 0x7fffu + lsb;
    return v.u >> 16;
}
__device__ __forceinline__ unsigned int pack2bf(float lo, float hi) {
    return f2bf(lo) | (f2bf(hi) << 16);
}

// Load 8 contiguous fp32, convert to bf16 bits packed in a uint4.
__device__ __forceinline__ uint4 load8cvt(const float* __restrict__ src) {
    const float4 a = ((const float4*)src)[0];
    const float4 b = ((const float4*)src)[1];
    uint4 r;
    r.x = pack2bf(a.x, a.y);
    r.y = pack2bf(a.z, a.w);
    r.z = pack2bf(b.x, b.y);
    r.w = pack2bf(b.z, b.w);
    return r;
}

__device__ __forceinline__ void storeC(float* p, float v) { *p = v; }
__device__ __forceinline__ void storeC(__hip_bfloat16* p, float v) { *p = __float2bfloat16(v); }

// Async global->LDS, 16B per lane. LDS dest is wave-uniform base + lane*16.
__device__ __forceinline__ void gload16(const unsigned short* g, unsigned short* l)
{
    __builtin_amdgcn_global_load_lds(
        (const __attribute__((address_space(1))) void*)g,
        (__attribute__((address_space(3))) void*)l,
        16, 0, 0);
}

// ---------------------------------------------------------------------------
// x fp32 -> bf16 (row-major copy-convert), 8 elems/thread
// ---------------------------------------------------------------------------
__global__ __launch_bounds__(256)
void convert_bf16(const float* __restrict__ X, unsigned short* __restrict__ Y, int total8)
{
    const int i = blockIdx.x * 256 + threadIdx.x;
    if (i >= total8) return;
    uint4 v = load8cvt(X + (size_t)i * 8);
    *(uint4*)(Y + (size_t)i * 8) = v;
}

// ---------------------------------------------------------------------------
// Weight transpose+convert: W fp32 [K,N] -> Wt bf16 [N,K]. 64x64 LDS tile.
// ---------------------------------------------------------------------------
__global__ __launch_bounds__(256)
void wtrans(const float* __restrict__ W, unsigned short* __restrict__ Wt, int K, int N)
{
    __shared__ float tile[64][65];
    const int n0 = blockIdx.x * 64;
    const int k0 = blockIdx.y * 64;
    const int t  = threadIdx.x;
    #pragma unroll
    for (int it = 0; it < 4; ++it) {
        const int seg = t + it * 256;          // 0..1023
        const int r   = seg >> 4;              // 0..63 (k)
        const int c   = (seg & 15) << 2;       // 0..60 (n)
        const float4 v = *(const float4*)&W[(size_t)(k0 + r) * N + n0 + c];
        tile[r][c]     = v.x;
        tile[r][c + 1] = v.y;
        tile[r][c + 2] = v.z;
        tile[r][c + 3] = v.w;
    }
    __syncthreads();
    const int n  = t >> 2;                     // 0..63
    const int ks = (t & 3) << 4;               // 0,16,32,48
    unsigned int ob[8];
    #pragma unroll
    for (int j = 0; j < 8; ++j)
        ob[j] = pack2bf(tile[ks + 2 * j][n], tile[ks + 2 * j + 1][n]);
    uint4* dst = (uint4*)&Wt[(size_t)(n0 + n) * K + k0 + ks];
    dst[0] = ((const uint4*)ob)[0];
    dst[1] = ((const uint4*)ob)[1];
}

// ---------------------------------------------------------------------------
// GEMM (m97 structure): C[M,N] = A[M,K] @ Bt[N,K]^T, both bf16.
// 128x128 tile, BK=32, 4 waves x (64x64), global_load_lds width-16 staging
// into linear LDS, both fragments k-contiguous ds_read_b128.
// XCD-aware bijective block swizzle (T1) when nwg % 8 == 0.
// ---------------------------------------------------------------------------
template <typename TC>
__global__ __launch_bounds__(256)
void gemm_bt(const unsigned short* __restrict__ A,   // [M,K] bf16
             const unsigned short* __restrict__ Bt,  // [N,K] bf16
             TC* __restrict__ C,
             int M, int N, int K)
{
    __shared__ unsigned short As[128 * 32];   // linear [row][k], no pad (gload_lds)
    __shared__ unsigned short Bs[128 * 32];   // linear [n][k]

    const int tid  = threadIdx.x;
    const int lane = tid & 63;
    const int w    = tid >> 6;
    const int wm   = (w >> 1) * 64;
    const int wn   = (w & 1) * 64;

    const int gx  = gridDim.x;
    const int nwg = gx * gridDim.y;
    int lid = blockIdx.y * gx + blockIdx.x;
    if ((nwg & 7) == 0) {                     // contiguous chunk per XCD
        const int q = nwg >> 3;
        lid = (lid & 7) * q + (lid >> 3);
    }
    const int m0 = (lid / gx) * 128;
    const int n0 = (lid % gx) * 128;

    const int fm   = lane & 15;
    const int fk   = (lane >> 4) * 8;

    floatx4 acc[4][4] = {};

    // staging: thread t covers flat shorts [t*8, t*8+8) (+2048 for 2nd issue)
    const int sr = tid >> 2;              // 0..63
    const int sk = (tid & 3) * 8;         // 0,8,16,24
    const unsigned short* ga0 = A  + (size_t)(m0 + sr) * K + sk;
    const unsigned short* ga1 = ga0 + (size_t)64 * K;
    const unsigned short* gb0 = Bt + (size_t)(n0 + sr) * K + sk;
    const unsigned short* gb1 = gb0 + (size_t)64 * K;
    unsigned short* lA = As + w * 512;    // wave-uniform LDS base (lane*16B added by HW)
    unsigned short* lB = Bs + w * 512;

    for (int k0 = 0; k0 < K; k0 += 32) {
        gload16(ga0 + k0, lA);
        gload16(ga1 + k0, lA + 2048);
        gload16(gb0 + k0, lB);
        gload16(gb1 + k0, lB + 2048);
        __syncthreads();   // drains vmcnt(0): tile resident

        short8 af[4], bf[4];
        #pragma unroll
        for (int i = 0; i < 4; ++i) {
            af[i] = *(const short8*)&As[(wm + i * 16 + fm) * 32 + fk];
            bf[i] = *(const short8*)&Bs[(wn + i * 16 + fm) * 32 + fk];
        }
        #pragma unroll
        for (int mi = 0; mi < 4; ++mi)
            #pragma unroll
            for (int ni = 0; ni < 4; ++ni)
                acc[mi][ni] = __builtin_amdgcn_mfma_f32_16x16x32_bf16(
                    af[mi], bf[ni], acc[mi][ni], 0, 0, 0);
        __syncthreads();   // all reads done before next iter's async LDS writes
    }

    const int cl = lane & 15;
    const int rq = (lane >> 4) * 4;
    #pragma unroll
    for (int mi = 0; mi < 4; ++mi) {
        #pragma unroll
        for (int ni = 0; ni < 4; ++ni) {
            const int col = n0 + wn + ni * 16 + cl;
            #pragma unroll
            for (int r = 0; r < 4; ++r) {
                const int row = m0 + wm + mi * 16 + rq + r;
                storeC(C + (size_t)row * N + col, acc[mi][ni][r]);
            }
        }
    }
}

// ---------------------------------------------------------------------------
// RoPE in-place on fused QKV (bf16): row bs, columns [coloff + h*128 .. ).
// cos/sin are fp32 [S,1,128].
// ---------------------------------------------------------------------------
__global__ void rope_kernel(unsigned short* __restrict__ T,
                            const float* __restrict__ cosb,
                            const float* __restrict__ sinb,
                            int NH, int coloff, int total)
{
    int idx = blockIdx.x * blockDim.x + threadIdx.x;
    if (idx >= total) return;
    const int dh   = idx & 63;
    const int rest = idx >> 6;
    const int h    = rest % NH;
    const int bs   = rest / NH;       // b*S + s
    const int s    = bs & (S_ - 1);
    const size_t base = (size_t)bs * QKVN_ + coloff + h * HD_;
    const float t1 = __bfloat162float(*(__hip_bfloat16*)&T[base + dh]);
    const float t2 = __bfloat162float(*(__hip_bfloat16*)&T[base + dh + 64]);
    const float c1 = cosb[s * HD_ + dh];
    const float s1 = sinb[s * HD_ + dh];
    const float c2 = cosb[s * HD_ + dh + 64];
    const float s2 = sinb[s * HD_ + dh + 64];
    T[base + dh]      = (unsigned short)f2bf(t1 * c1 - t2 * s1);
    T[base + dh + 64] = (unsigned short)f2bf(t2 * c2 + t1 * s2);
}

// ---------------------------------------------------------------------------
// MFMA flash attention on fused QKV layout (row stride 6144).
// Round-3 structure:
//  * qt-PAIRING: block bx processes qt=15-bx then qt=bx -> uniform 34
//    k-tile-units per block; grid 8x64 = 512 blocks (2/CU). Kills causal tail.
//  * row-sum via ones-MFMA (P @ 1), rescaled by alpha like o_acc -> no sum
//    shuffle-reduce, no l bookkeeping.
//  * scale folded into exp args; mask hoisted behind wave-uniform needmask;
//    fully-masked wave-tiles skip compute.
//  * defer-max (THR = 8/scale): wave-uniform skip of the alpha rescale pass.
//  * coalesced O epilogue via LDS bounce (uint4 stores).
// ---------------------------------------------------------------------------
__global__ __launch_bounds__(256)
void attn_mfma(const unsigned short* __restrict__ QKV,
               __hip_bfloat16* __restrict__ O)
{
    const int bx = blockIdx.x;          // 0..7
    const int bh = blockIdx.y;          // 0..63
    const int b  = bh >> 5;
    const int h  = bh & 31;
    const int g  = h >> 2;              // kv head

    // Flat LDS: Ks [64][136] | Vt [128][72] | Ps [4][32][72]  (54272 B)
    __shared__ unsigned short lds[27136];
    unsigned short* KsF = lds;                  // key-major, +8 pad
    unsigned short* VtF = lds + 8704;           // [d][key ^ ((d>>5)<<4)]
    unsigned short* PsF = lds + 17920;          // per-wave P, col ^ (quad<<3)
    unsigned short* Es  = lds;                  // epilogue bounce [4][32][136]

    const int tid  = threadIdx.x;
    const int lane = tid & 63;
    const int w    = tid >> 6;
    const int fm   = lane & 15;
    const int quad = lane >> 4;
    const int fk   = quad * 8;

    const float scale = 0.08838834764831845f;   // 1/sqrt(128)
    short8 ones;
    #pragma unroll
    for (int j = 0; j < 8; ++j) ones[j] = (short)0x3F80;   // bf16 1.0

    // K/V staging geometry (qt-independent)
    const int key  = tid >> 2;                   // 0..63
    const int d0   = (tid & 3) * 32;
    const int vcol = key ^ ((tid & 3) << 4);     // Vt write swizzle
    const unsigned short* Kp = QKV + DIM_ + g * HD_;          // K section
    const unsigned short* Vp = QKV + DIM_ + KVD_ + g * HD_;   // V section
    const size_t gbase = (size_t)(b * S_ + key) * QKVN_ + d0;
    const size_t gstep = (size_t)64 * QKVN_;
    uint4 kreg[4], vreg[4];

    for (int pass = 0; pass < 2; ++pass) {
        const int qt = pass ? bx : (15 - bx);    // heavy half first
        const int q0 = qt * 128;
        const int qrow_base = q0 + w * 32;

        // Q A-fragments for this q-tile
        short8 qf[2][4];
        #pragma unroll
        for (int mt = 0; mt < 2; ++mt) {
            const int row = qrow_base + mt * 16 + fm;
            const unsigned short* qp = QKV + (size_t)(b * S_ + row) * QKVN_ + h * HD_;
            #pragma unroll
            for (int dt = 0; dt < 4; ++dt)
                qf[mt][dt] = *(const short8*)(qp + dt * 32 + fk);
        }

        floatx4 o_acc[2][8] = {};
        floatx4 sum_acc[2] = {};
        float m_r[2][4];
        #pragma unroll
        for (int mt = 0; mt < 2; ++mt)
            #pragma unroll
            for (int r = 0; r < 4; ++r) m_r[mt][r] = -1e30f;

        const int ktiles = 2 * (qt + 1);
        {   // prefetch tile 0
            const uint4* kp = (const uint4*)(Kp + gbase);
            const uint4* vp = (const uint4*)(Vp + gbase);
            #pragma unroll
            for (int i = 0; i < 4; ++i) { kreg[i] = kp[i]; vreg[i] = vp[i]; }
        }

        for (int kt = 0; kt < ktiles; ++kt) {
            const int k0 = kt * 64;
            __syncthreads();   // prior LDS reads (incl. epilogue/pass-0) complete
            {   // write prefetched K (row-major) and V (transposed, swizzled)
                *(uint4*)&KsF[key * 136 + d0]      = kreg[0];
                *(uint4*)&KsF[key * 136 + d0 + 8]  = kreg[1];
                *(uint4*)&KsF[key * 136 + d0 + 16] = kreg[2];
                *(uint4*)&KsF[key * 136 + d0 + 24] = kreg[3];
                const unsigned short* vs = (const unsigned short*)vreg;
                #pragma unroll
                for (int i = 0; i < 32; ++i)
                    VtF[(d0 + i) * 72 + vcol] = vs[i];
            }
            __syncthreads();
            if (kt + 1 < ktiles) {   // prefetch next tile under compute
                const uint4* kp = (const uint4*)(Kp + gbase + (size_t)(kt + 1) * gstep);
                const uint4* vp = (const uint4*)(Vp + gbase + (size_t)(kt + 1) * gstep);
                #pragma unroll
                for (int i = 0; i < 4; ++i) { kreg[i] = kp[i]; vreg[i] = vp[i]; }
            }

            if (k0 > qrow_base + 31) continue;   // wave fully masked: skip compute

            // ---- QK^T (raw scores; scale folded into exp later) ----
            floatx4 s_acc[2][4] = {};
            #pragma unroll
            for (int dt = 0; dt < 4; ++dt) {
                #pragma unroll
                for (int nt = 0; nt < 4; ++nt) {
                    short8 bfr = *(const short8*)&KsF[(nt * 16 + fm) * 136 + dt * 32 + fk];
                    #pragma unroll
                    for (int mt = 0; mt < 2; ++mt)
                        s_acc[mt][nt] = __builtin_amdgcn_mfma_f32_16x16x32_bf16(
                            qf[mt][dt], bfr, s_acc[mt][nt], 0, 0, 0);
                }
            }

            // ---- mask + online softmax ----
            const bool needmask = (k0 + 63 > qrow_base);
            #pragma unroll
            for (int mt = 0; mt < 2; ++mt) {
                const int rowq0 = qrow_base + mt * 16 + quad * 4;
                #pragma unroll
                for (int r = 0; r < 4; ++r) {
                    if (needmask) {
                        const int rowq = rowq0 + r;
                        #pragma unroll
                        for (int nt = 0; nt < 4; ++nt) {
                            const int c = k0 + nt * 16 + fm;
                            if (c > rowq) s_acc[mt][nt][r] = -1e30f;
                        }
                    }
                    float mx = fmaxf(fmaxf(s_acc[mt][0][r], s_acc[mt][1][r]),
                                     fmaxf(s_acc[mt][2][r], s_acc[mt][3][r]));
                    #pragma unroll
                    for (int off = 1; off < 16; off <<= 1)
                        mx = fmaxf(mx, __shfl_xor(mx, off));
                    float mcur = m_r[mt][r];
                    if (__any(mx > mcur + 90.5f)) {   // defer-max: rescale only on growth
                        const float mnew = fmaxf(mcur, mx);
                        const float alpha = __expf((mcur - mnew) * scale);
                        #pragma unroll
                        for (int nt = 0; nt < 8; ++nt)
                            o_acc[mt][nt][r] *= alpha;
                        sum_acc[mt][r] *= alpha;
                        m_r[mt][r] = mnew;
                        mcur = mnew;
                    }
                    const int prow = mt * 16 + quad * 4 + r;
                    #pragma unroll
                    for (int nt = 0; nt < 4; ++nt) {
                        const float p = __expf((s_acc[mt][nt][r] - mcur) * scale);
                        PsF[(w * 32 + prow) * 72 + ((nt * 16 + fm) ^ (quad << 3))] =
                            (unsigned short)f2bf(p);
                    }
                }
            }

            // ---- PV + row-sum (ones-MFMA) ----
            #pragma unroll
            for (int ct = 0; ct < 2; ++ct) {
                short8 af[2];
                #pragma unroll
                for (int mt = 0; mt < 2; ++mt)
                    af[mt] = *(const short8*)
                        &PsF[(w * 32 + mt * 16 + fm) * 72 + ct * 32 + ((quad ^ (fm >> 2)) << 3)];
                #pragma unroll
                for (int mt = 0; mt < 2; ++mt)
                    sum_acc[mt] = __builtin_amdgcn_mfma_f32_16x16x32_bf16(
                        af[mt], ones, sum_acc[mt], 0, 0, 0);
                #pragma unroll
                for (int nt = 0; nt < 8; ++nt) {
                    short8 bfr = *(const short8*)
                        &VtF[(nt * 16 + fm) * 72 + ((ct * 32 + fk) ^ ((nt >> 1) << 4))];
                    #pragma unroll
                    for (int mt = 0; mt < 2; ++mt)
                        o_acc[mt][nt] = __builtin_amdgcn_mfma_f32_16x16x32_bf16(
                            af[mt], bfr, o_acc[mt][nt], 0, 0, 0);
                }
            }
        }

        // ---- epilogue: normalize, bounce through LDS, coalesced uint4 stores ----
        __syncthreads();   // all waves done with Ks/Vt before Es overwrites them
        unsigned short* Ew = Es + w * (32 * 136);
        #pragma unroll
        for (int mt = 0; mt < 2; ++mt) {
            #pragma unroll
            for (int r = 0; r < 4; ++r) {
                const float inv_l = 1.f / sum_acc[mt][r];
                const int prow = mt * 16 + quad * 4 + r;
                #pragma unroll
                for (int nt = 0; nt < 8; ++nt)
                    Ew[prow * 136 + nt * 16 + fm] =
                        (unsigned short)f2bf(o_acc[mt][nt][r] * inv_l);
            }
        }
        __syncthreads();
        #pragma unroll
        for (int mt = 0; mt < 2; ++mt) {
            const int rowE = mt * 16 + fm;
            const unsigned short* src = Ew + rowE * 136 + quad * 32;
            __hip_bfloat16* op = O + ((size_t)(b * S_ + qrow_base + rowE) * H_ + h) * HD_
                                   + quad * 32;
            uint4 v0 = *(const uint4*)(src);
            uint4 v1 = *(const uint4*)(src + 8);
            uint4 v2 = *(const uint4*)(src + 16);
            uint4 v3 = *(const uint4*)(src + 24);
            *(uint4*)(op)      = v0;
            *(uint4*)(op + 8)  = v1;
            *(uint4*)(op + 16) = v2;
            *(uint4*)(op + 24) = v3;
        }
        // next pass's loop-top __syncthreads covers Es reads vs. restaging
    }
}

// ---------------------------------------------------------------------------
extern "C" void kernel_launch(void* const* d_in, const int* in_sizes, int n_in,
                              void* d_out, int out_size, void* d_ws, size_t ws_size,
                              hipStream_t stream)
{
    const float* x    = (const float*)d_in[0];
    const float* cosb = (const float*)d_in[1];
    const float* sinb = (const float*)d_in[2];
    const float* Wq   = (const float*)d_in[3];
    const float* Wk   = (const float*)d_in[4];
    const float* Wv   = (const float*)d_in[5];
    const float* Wo   = (const float*)d_in[6];
    float* out = (float*)d_out;

    // Workspace layout (128 MB, slots reused along the stream timeline):
    //  [0,32)   Xb (x bf16)          -> dead after QKV gemm -> Ab (attn out)
    //  [32,80)  WT (fused WqT|WkT|WvT [6144,4096]) -> dead after QKV gemm
    //           -> WoT at [32,64)
    //  [80,128) QKV (fused [4096,6144] bf16)
    char* ws = (char*)d_ws;
    const size_t MB = 1024 * 1024;
    unsigned short* Xb  = (unsigned short*)(ws);
    unsigned short* Ab  = (unsigned short*)(ws);
    unsigned short* WT  = (unsigned short*)(ws + 32 * MB);
    unsigned short* WoT = (unsigned short*)(ws + 32 * MB);
    unsigned short* QKV = (unsigned short*)(ws + 80 * MB);

    unsigned short* WTq = WT;
    unsigned short* WTk = WT + (size_t)DIM_ * DIM_;           // rows 4096..5119
    unsigned short* WTv = WT + (size_t)(DIM_ + KVD_) * DIM_;  // rows 5120..6143

    dim3 blk(256);

    // 1. x -> bf16 (shared A operand for QKV projection)
    convert_bf16<<<dim3((MROWS_ * DIM_) / 8 / 256), blk, 0, stream>>>(
        x, Xb, (MROWS_ * DIM_) / 8);

    // 2. weight transpose+convert into fused WT: [K,N] fp32 -> [N,K] bf16
    wtrans<<<dim3(DIM_ / 64, DIM_ / 64), blk, 0, stream>>>(Wq, WTq, DIM_, DIM_);
    wtrans<<<dim3(KVD_ / 64, DIM_ / 64), blk, 0, stream>>>(Wk, WTk, DIM_, KVD_);
    wtrans<<<dim3(KVD_ / 64, DIM_ / 64), blk, 0, stream>>>(Wv, WTv, DIM_, KVD_);

    // 3. fused QKV projection: [4096,4096] @ [4096,6144] -> [4096,6144] bf16
    gemm_bt<__hip_bfloat16><<<dim3(QKVN_ / 128, MROWS_ / 128), blk, 0, stream>>>(
        Xb, WT, (__hip_bfloat16*)QKV, MROWS_, QKVN_, DIM_);

    // 4. Wo transpose into WT's (now dead) slot
    wtrans<<<dim3(DIM_ / 64, DIM_ / 64), blk, 0, stream>>>(Wo, WoT, DIM_, DIM_);

    // 5. RoPE in-place on fused QKV (Q section then K section)
    {
        int totq = MROWS_ * H_ * 64;
        int totk = MROWS_ * KV_ * 64;
        rope_kernel<<<(totq + 255) / 256, blk, 0, stream>>>(
            QKV, cosb, sinb, H_, 0, totq);
        rope_kernel<<<(totk + 255) / 256, blk, 0, stream>>>(
            QKV, cosb, sinb, KV_, DIM_, totk);
    }

    // 6. MFMA flash attention -> Ab (Xb slot, dead after QKV gemm)
    attn_mfma<<<dim3(8, B_ * H_), blk, 0, stream>>>(
        QKV, (__hip_bfloat16*)Ab);

    // 7. output projection: Ab bf16 @ WoT -> fp32 out
    gemm_bt<float><<<dim3(DIM_ / 128, MROWS_ / 128), blk, 0, stream>>>(
        Ab, WoT, out, MROWS_, DIM_, DIM_);
}

// Round 4
// 1081.384 us; speedup vs baseline: 1.6469x; 1.0184x over previous
//
#include <hip/hip_runtime.h>
#include <hip/hip_bf16.h>

// Problem constants
#define B_   2
#define S_   2048
#define DIM_ 4096
#define H_   32
#define KV_  8
#define HD_  128
#define MROWS_ (B_ * S_)   // 4096
#define KVD_ (KV_ * HD_)   // 1024
#define QKVN_ (DIM_ + 2 * KVD_)   // 6144, fused QKV row stride

typedef __attribute__((ext_vector_type(8))) short short8;
typedef __attribute__((ext_vector_type(4))) float floatx4;

// fp32 -> bf16 bits, round-to-nearest-even (inputs are finite; no NaN path)
__device__ __forceinline__ unsigned int f2bf(float f) {
    union { float f; unsigned int u; } v; v.f = f;
    unsigned int lsb = (v.u >> 16) & 1u;
    v.u += 0x7fffu + lsb;
    return v.u >> 16;
}
__device__ __forceinline__ unsigned int pack2bf(float lo, float hi) {
    return f2bf(lo) | (f2bf(hi) << 16);
}

// Load 8 contiguous fp32, convert to bf16 bits packed in a uint4.
__device__ __forceinline__ uint4 load8cvt(const float* __restrict__ src) {
    const float4 a = ((const float4*)src)[0];
    const float4 b = ((const float4*)src)[1];
    uint4 r;
    r.x = pack2bf(a.x, a.y);
    r.y = pack2bf(a.z, a.w);
    r.z = pack2bf(b.x, b.y);
    r.w = pack2bf(b.z, b.w);
    return r;
}

__device__ __forceinline__ void storeC(float* p, float v) { *p = v; }
__device__ __forceinline__ void storeC(__hip_bfloat16* p, float v) { *p = __float2bfloat16(v); }

// Async global->LDS, 16B per lane. LDS dest is wave-uniform base + lane*16.
__device__ __forceinline__ void gload16(const unsigned short* g, unsigned short* l)
{
    __builtin_amdgcn_global_load_lds(
        (const __attribute__((address_space(1))) void*)g,
        (__attribute__((address_space(3))) void*)l,
        16, 0, 0);
}

// ---------------------------------------------------------------------------
// x fp32 -> bf16 (row-major copy-convert), 8 elems/thread
// ---------------------------------------------------------------------------
__global__ __launch_bounds__(256)
void convert_bf16(const float* __restrict__ X, unsigned short* __restrict__ Y, int total8)
{
    const int i = blockIdx.x * 256 + threadIdx.x;
    if (i >= total8) return;
    uint4 v = load8cvt(X + (size_t)i * 8);
    *(uint4*)(Y + (size_t)i * 8) = v;
}

// ---------------------------------------------------------------------------
// Weight transpose+convert: W fp32 [K,N] -> Wt bf16 [N,K]. 64x64 LDS tile.
// ---------------------------------------------------------------------------
__global__ __launch_bounds__(256)
void wtrans(const float* __restrict__ W, unsigned short* __restrict__ Wt, int K, int N)
{
    __shared__ float tile[64][65];
    const int n0 = blockIdx.x * 64;
    const int k0 = blockIdx.y * 64;
    const int t  = threadIdx.x;
    #pragma unroll
    for (int it = 0; it < 4; ++it) {
        const int seg = t + it * 256;          // 0..1023
        const int r   = seg >> 4;              // 0..63 (k)
        const int c   = (seg & 15) << 2;       // 0..60 (n)
        const float4 v = *(const float4*)&W[(size_t)(k0 + r) * N + n0 + c];
        tile[r][c]     = v.x;
        tile[r][c + 1] = v.y;
        tile[r][c + 2] = v.z;
        tile[r][c + 3] = v.w;
    }
    __syncthreads();
    const int n  = t >> 2;                     // 0..63
    const int ks = (t & 3) << 4;               // 0,16,32,48
    unsigned int ob[8];
    #pragma unroll
    for (int j = 0; j < 8; ++j)
        ob[j] = pack2bf(tile[ks + 2 * j][n], tile[ks + 2 * j + 1][n]);
    uint4* dst = (uint4*)&Wt[(size_t)(n0 + n) * K + k0 + ks];
    dst[0] = ((const uint4*)ob)[0];
    dst[1] = ((const uint4*)ob)[1];
}

// ---------------------------------------------------------------------------
// GEMM, 256x256 tile (T2+T3+T4+T5 stack): C[M,N] = A[M,K] @ Bt[N,K]^T.
// 512 threads = 8 waves (2M x 4N), per-wave 128x64 output, BK=64.
// Double-buffered 128 KiB LDS; global_load_lds width-16 into LINEAR dest
// with chunk-swizzled GLOBAL source (rule 21); ds_read_b128 with matching
// swizzle (16-way -> 4-way bank conflict). Counted vmcnt(8) (2 K-tiles in
// flight, never drained mid-loop) + raw s_barrier + sched_barrier fences.
// setprio(1) around MFMA clusters.
// ---------------------------------------------------------------------------
template <typename TC>
__global__ __launch_bounds__(512)
void gemm256(const unsigned short* __restrict__ A,   // [M,K] bf16
             const unsigned short* __restrict__ Bt,  // [N,K] bf16
             TC* __restrict__ C,
             int M, int N, int K)
{
    __shared__ unsigned short As[2][16384];   // [dbuf][256 rows x 64 k] 32KB each
    __shared__ unsigned short Bs[2][16384];

    const int tid  = threadIdx.x;
    const int lane = tid & 63;
    const int w    = tid >> 6;          // 0..7
    const int wm   = (w >> 2) * 128;    // wave M offset
    const int wn   = (w & 3) * 64;      // wave N offset
    const int fm   = lane & 15;
    const int quad = lane >> 4;

    const int gx  = gridDim.x;
    const int nwg = gx * gridDim.y;
    int lid = blockIdx.y * gx + blockIdx.x;
    if ((nwg & 7) == 0) {                     // XCD-contiguous chunks (bijective)
        const int q = nwg >> 3;
        lid = (lid & 7) * q + (lid >> 3);
    }
    const int m0 = (lid / gx) * 256;
    const int n0 = (lid % gx) * 256;

    floatx4 acc[8][4] = {};

    // Staging: thread t covers LDS bytes [i*8192 + t*16) of each half.
    // LDS row = i*64 + (t>>3); phys chunk = t&7; swizzle s(row) = (row>>2)&3
    // = (t>>5)&3; logical (global) chunk = phys ^ s.
    const int rowb = tid >> 3;                              // 0..63
    const int koff = ((tid & 7) ^ ((tid >> 5) & 3)) * 8;    // pre-swizzled k
    const unsigned short* gA = A  + (size_t)(m0 + rowb) * K + koff;
    const unsigned short* gB = Bt + (size_t)(n0 + rowb) * K + koff;
    const int NT = K >> 6;

#define STAGE256(kt, sel) do {                                                \
    const size_t ko_ = (size_t)(kt) * 64;                                     \
    _Pragma("unroll")                                                         \
    for (int i_ = 0; i_ < 4; ++i_)                                            \
        gload16(gA + (size_t)(i_ * 64) * K + ko_, &As[sel][i_ * 4096 + w * 512]); \
    _Pragma("unroll")                                                         \
    for (int i_ = 0; i_ < 4; ++i_)                                            \
        gload16(gB + (size_t)(i_ * 64) * K + ko_, &Bs[sel][i_ * 4096 + w * 512]); \
} while (0)

    STAGE256(0, 0);
    STAGE256(1, 1);         // 16 loads outstanding per wave

    for (int kt = 0; kt < NT; ++kt) {
        if (kt + 1 < NT) { asm volatile("s_waitcnt vmcnt(8)" ::: "memory"); }
        else             { asm volatile("s_waitcnt vmcnt(0)" ::: "memory"); }
        __builtin_amdgcn_s_barrier();          // tile kt resident for ALL waves
        __builtin_amdgcn_sched_barrier(0);     // no ds_read hoisted above

        const unsigned short* bufA = As[kt & 1];
        const unsigned short* bufB = Bs[kt & 1];
        #pragma unroll
        for (int win = 0; win < 2; ++win) {    // two K=32 windows
            const int pc = ((win * 4 + quad) ^ (fm >> 2)) * 8;  // swizzled chunk
            short8 afr[8], bfr[4];
            #pragma unroll
            for (int mi = 0; mi < 8; ++mi)
                afr[mi] = *(const short8*)&bufA[(wm + mi * 16 + fm) * 64 + pc];
            #pragma unroll
            for (int ni = 0; ni < 4; ++ni)
                bfr[ni] = *(const short8*)&bufB[(wn + ni * 16 + fm) * 64 + pc];
            __builtin_amdgcn_s_setprio(1);
            #pragma unroll
            for (int mi = 0; mi < 8; ++mi)
                #pragma unroll
                for (int ni = 0; ni < 4; ++ni)
                    acc[mi][ni] = __builtin_amdgcn_mfma_f32_16x16x32_bf16(
                        afr[mi], bfr[ni], acc[mi][ni], 0, 0, 0);
            __builtin_amdgcn_s_setprio(0);
        }
        asm volatile("s_waitcnt lgkmcnt(0)" ::: "memory");   // LDS reads drained
        __builtin_amdgcn_s_barrier();          // all waves done reading buf
        __builtin_amdgcn_sched_barrier(0);     // no gload hoisted above
        if (kt + 2 < NT) STAGE256(kt + 2, kt & 1);
    }
#undef STAGE256

    const int cl = fm;
    const int rq = quad * 4;
    #pragma unroll
    for (int mi = 0; mi < 8; ++mi) {
        #pragma unroll
        for (int ni = 0; ni < 4; ++ni) {
            const int col = n0 + wn + ni * 16 + cl;
            #pragma unroll
            for (int r = 0; r < 4; ++r) {
                const int row = m0 + wm + mi * 16 + rq + r;
                storeC(C + (size_t)row * N + col, acc[mi][ni][r]);
            }
        }
    }
}

// ---------------------------------------------------------------------------
// RoPE in-place on fused QKV (bf16): row bs, columns [coloff + h*128 .. ).
// cos/sin are fp32 [S,1,128].
// ---------------------------------------------------------------------------
__global__ void rope_kernel(unsigned short* __restrict__ T,
                            const float* __restrict__ cosb,
                            const float* __restrict__ sinb,
                            int NH, int coloff, int total)
{
    int idx = blockIdx.x * blockDim.x + threadIdx.x;
    if (idx >= total) return;
    const int dh   = idx & 63;
    const int rest = idx >> 6;
    const int h    = rest % NH;
    const int bs   = rest / NH;       // b*S + s
    const int s    = bs & (S_ - 1);
    const size_t base = (size_t)bs * QKVN_ + coloff + h * HD_;
    const float t1 = __bfloat162float(*(__hip_bfloat16*)&T[base + dh]);
    const float t2 = __bfloat162float(*(__hip_bfloat16*)&T[base + dh + 64]);
    const float c1 = cosb[s * HD_ + dh];
    const float s1 = sinb[s * HD_ + dh];
    const float c2 = cosb[s * HD_ + dh + 64];
    const float s2 = sinb[s * HD_ + dh + 64];
    T[base + dh]      = (unsigned short)f2bf(t1 * c1 - t2 * s1);
    T[base + dh + 64] = (unsigned short)f2bf(t2 * c2 + t1 * s2);
}

// ---------------------------------------------------------------------------
// MFMA flash attention on fused QKV layout (row stride 6144).
// qt-pairing load balance; ones-MFMA row-sum; defer-max; masked-tile skip;
// coalesced LDS-bounce epilogue. (Unchanged from round 3.)
// ---------------------------------------------------------------------------
__global__ __launch_bounds__(256)
void attn_mfma(const unsigned short* __restrict__ QKV,
               __hip_bfloat16* __restrict__ O)
{
    const int bx = blockIdx.x;          // 0..7
    const int bh = blockIdx.y;          // 0..63
    const int b  = bh >> 5;
    const int h  = bh & 31;
    const int g  = h >> 2;              // kv head

    // Flat LDS: Ks [64][136] | Vt [128][72] | Ps [4][32][72]  (54272 B)
    __shared__ unsigned short lds[27136];
    unsigned short* KsF = lds;                  // key-major, +8 pad
    unsigned short* VtF = lds + 8704;           // [d][key ^ ((d>>5)<<4)]
    unsigned short* PsF = lds + 17920;          // per-wave P, col ^ (quad<<3)
    unsigned short* Es  = lds;                  // epilogue bounce [4][32][136]

    const int tid  = threadIdx.x;
    const int lane = tid & 63;
    const int w    = tid >> 6;
    const int fm   = lane & 15;
    const int quad = lane >> 4;
    const int fk   = quad * 8;

    const float scale = 0.08838834764831845f;   // 1/sqrt(128)
    short8 ones;
    #pragma unroll
    for (int j = 0; j < 8; ++j) ones[j] = (short)0x3F80;   // bf16 1.0

    // K/V staging geometry (qt-independent)
    const int key  = tid >> 2;                   // 0..63
    const int d0   = (tid & 3) * 32;
    const int vcol = key ^ ((tid & 3) << 4);     // Vt write swizzle
    const unsigned short* Kp = QKV + DIM_ + g * HD_;          // K section
    const unsigned short* Vp = QKV + DIM_ + KVD_ + g * HD_;   // V section
    const size_t gbase = (size_t)(b * S_ + key) * QKVN_ + d0;
    const size_t gstep = (size_t)64 * QKVN_;
    uint4 kreg[4], vreg[4];

    for (int pass = 0; pass < 2; ++pass) {
        const int qt = pass ? bx : (15 - bx);    // heavy half first
        const int q0 = qt * 128;
        const int qrow_base = q0 + w * 32;

        // Q A-fragments for this q-tile
        short8 qf[2][4];
        #pragma unroll
        for (int mt = 0; mt < 2; ++mt) {
            const int row = qrow_base + mt * 16 + fm;
            const unsigned short* qp = QKV + (size_t)(b * S_ + row) * QKVN_ + h * HD_;
            #pragma unroll
            for (int dt = 0; dt < 4; ++dt)
                qf[mt][dt] = *(const short8*)(qp + dt * 32 + fk);
        }

        floatx4 o_acc[2][8] = {};
        floatx4 sum_acc[2] = {};
        float m_r[2][4];
        #pragma unroll
        for (int mt = 0; mt < 2; ++mt)
            #pragma unroll
            for (int r = 0; r < 4; ++r) m_r[mt][r] = -1e30f;

        const int ktiles = 2 * (qt + 1);
        {   // prefetch tile 0
            const uint4* kp = (const uint4*)(Kp + gbase);
            const uint4* vp = (const uint4*)(Vp + gbase);
            #pragma unroll
            for (int i = 0; i < 4; ++i) { kreg[i] = kp[i]; vreg[i] = vp[i]; }
        }

        for (int kt = 0; kt < ktiles; ++kt) {
            const int k0 = kt * 64;
            __syncthreads();   // prior LDS reads (incl. epilogue/pass-0) complete
            {   // write prefetched K (row-major) and V (transposed, swizzled)
                *(uint4*)&KsF[key * 136 + d0]      = kreg[0];
                *(uint4*)&KsF[key * 136 + d0 + 8]  = kreg[1];
                *(uint4*)&KsF[key * 136 + d0 + 16] = kreg[2];
                *(uint4*)&KsF[key * 136 + d0 + 24] = kreg[3];
                const unsigned short* vs = (const unsigned short*)vreg;
                #pragma unroll
                for (int i = 0; i < 32; ++i)
                    VtF[(d0 + i) * 72 + vcol] = vs[i];
            }
            __syncthreads();
            if (kt + 1 < ktiles) {   // prefetch next tile under compute
                const uint4* kp = (const uint4*)(Kp + gbase + (size_t)(kt + 1) * gstep);
                const uint4* vp = (const uint4*)(Vp + gbase + (size_t)(kt + 1) * gstep);
                #pragma unroll
                for (int i = 0; i < 4; ++i) { kreg[i] = kp[i]; vreg[i] = vp[i]; }
            }

            if (k0 > qrow_base + 31) continue;   // wave fully masked: skip compute

            // ---- QK^T (raw scores; scale folded into exp later) ----
            floatx4 s_acc[2][4] = {};
            #pragma unroll
            for (int dt = 0; dt < 4; ++dt) {
                #pragma unroll
                for (int nt = 0; nt < 4; ++nt) {
                    short8 bfr = *(const short8*)&KsF[(nt * 16 + fm) * 136 + dt * 32 + fk];
                    #pragma unroll
                    for (int mt = 0; mt < 2; ++mt)
                        s_acc[mt][nt] = __builtin_amdgcn_mfma_f32_16x16x32_bf16(
                            qf[mt][dt], bfr, s_acc[mt][nt], 0, 0, 0);
                }
            }

            // ---- mask + online softmax ----
            const bool needmask = (k0 + 63 > qrow_base);
            #pragma unroll
            for (int mt = 0; mt < 2; ++mt) {
                const int rowq0 = qrow_base + mt * 16 + quad * 4;
                #pragma unroll
                for (int r = 0; r < 4; ++r) {
                    if (needmask) {
                        const int rowq = rowq0 + r;
                        #pragma unroll
                        for (int nt = 0; nt < 4; ++nt) {
                            const int c = k0 + nt * 16 + fm;
                            if (c > rowq) s_acc[mt][nt][r] = -1e30f;
                        }
                    }
                    float mx = fmaxf(fmaxf(s_acc[mt][0][r], s_acc[mt][1][r]),
                                     fmaxf(s_acc[mt][2][r], s_acc[mt][3][r]));
                    #pragma unroll
                    for (int off = 1; off < 16; off <<= 1)
                        mx = fmaxf(mx, __shfl_xor(mx, off));
                    float mcur = m_r[mt][r];
                    if (__any(mx > mcur + 90.5f)) {   // defer-max: rescale only on growth
                        const float mnew = fmaxf(mcur, mx);
                        const float alpha = __expf((mcur - mnew) * scale);
                        #pragma unroll
                        for (int nt = 0; nt < 8; ++nt)
                            o_acc[mt][nt][r] *= alpha;
                        sum_acc[mt][r] *= alpha;
                        m_r[mt][r] = mnew;
                        mcur = mnew;
                    }
                    const int prow = mt * 16 + quad * 4 + r;
                    #pragma unroll
                    for (int nt = 0; nt < 4; ++nt) {
                        const float p = __expf((s_acc[mt][nt][r] - mcur) * scale);
                        PsF[(w * 32 + prow) * 72 + ((nt * 16 + fm) ^ (quad << 3))] =
                            (unsigned short)f2bf(p);
                    }
                }
            }

            // ---- PV + row-sum (ones-MFMA) ----
            #pragma unroll
            for (int ct = 0; ct < 2; ++ct) {
                short8 af[2];
                #pragma unroll
                for (int mt = 0; mt < 2; ++mt)
                    af[mt] = *(const short8*)
                        &PsF[(w * 32 + mt * 16 + fm) * 72 + ct * 32 + ((quad ^ (fm >> 2)) << 3)];
                #pragma unroll
                for (int mt = 0; mt < 2; ++mt)
                    sum_acc[mt] = __builtin_amdgcn_mfma_f32_16x16x32_bf16(
                        af[mt], ones, sum_acc[mt], 0, 0, 0);
                #pragma unroll
                for (int nt = 0; nt < 8; ++nt) {
                    short8 bfr = *(const short8*)
                        &VtF[(nt * 16 + fm) * 72 + ((ct * 32 + fk) ^ ((nt >> 1) << 4))];
                    #pragma unroll
                    for (int mt = 0; mt < 2; ++mt)
                        o_acc[mt][nt] = __builtin_amdgcn_mfma_f32_16x16x32_bf16(
                            af[mt], bfr, o_acc[mt][nt], 0, 0, 0);
                }
            }
        }

        // ---- epilogue: normalize, bounce through LDS, coalesced uint4 stores ----
        __syncthreads();   // all waves done with Ks/Vt before Es overwrites them
        unsigned short* Ew = Es + w * (32 * 136);
        #pragma unroll
        for (int mt = 0; mt < 2; ++mt) {
            #pragma unroll
            for (int r = 0; r < 4; ++r) {
                const float inv_l = 1.f / sum_acc[mt][r];
                const int prow = mt * 16 + quad * 4 + r;
                #pragma unroll
                for (int nt = 0; nt < 8; ++nt)
                    Ew[prow * 136 + nt * 16 + fm] =
                        (unsigned short)f2bf(o_acc[mt][nt][r] * inv_l);
            }
        }
        __syncthreads();
        #pragma unroll
        for (int mt = 0; mt < 2; ++mt) {
            const int rowE = mt * 16 + fm;
            const unsigned short* src = Ew + rowE * 136 + quad * 32;
            __hip_bfloat16* op = O + ((size_t)(b * S_ + qrow_base + rowE) * H_ + h) * HD_
                                   + quad * 32;
            uint4 v0 = *(const uint4*)(src);
            uint4 v1 = *(const uint4*)(src + 8);
            uint4 v2 = *(const uint4*)(src + 16);
            uint4 v3 = *(const uint4*)(src + 24);
            *(uint4*)(op)      = v0;
            *(uint4*)(op + 8)  = v1;
            *(uint4*)(op + 16) = v2;
            *(uint4*)(op + 24) = v3;
        }
        // next pass's loop-top __syncthreads covers Es reads vs. restaging
    }
}

// ---------------------------------------------------------------------------
extern "C" void kernel_launch(void* const* d_in, const int* in_sizes, int n_in,
                              void* d_out, int out_size, void* d_ws, size_t ws_size,
                              hipStream_t stream)
{
    const float* x    = (const float*)d_in[0];
    const float* cosb = (const float*)d_in[1];
    const float* sinb = (const float*)d_in[2];
    const float* Wq   = (const float*)d_in[3];
    const float* Wk   = (const float*)d_in[4];
    const float* Wv   = (const float*)d_in[5];
    const float* Wo   = (const float*)d_in[6];
    float* out = (float*)d_out;

    // Workspace layout (128 MB, slots reused along the stream timeline):
    //  [0,32)   Xb (x bf16)          -> dead after QKV gemm -> Ab (attn out)
    //  [32,80)  WT (fused WqT|WkT|WvT [6144,4096]) -> dead after QKV gemm
    //           -> WoT at [32,64)
    //  [80,128) QKV (fused [4096,6144] bf16)
    char* ws = (char*)d_ws;
    const size_t MB = 1024 * 1024;
    unsigned short* Xb  = (unsigned short*)(ws);
    unsigned short* Ab  = (unsigned short*)(ws);
    unsigned short* WT  = (unsigned short*)(ws + 32 * MB);
    unsigned short* WoT = (unsigned short*)(ws + 32 * MB);
    unsigned short* QKV = (unsigned short*)(ws + 80 * MB);

    unsigned short* WTq = WT;
    unsigned short* WTk = WT + (size_t)DIM_ * DIM_;           // rows 4096..5119
    unsigned short* WTv = WT + (size_t)(DIM_ + KVD_) * DIM_;  // rows 5120..6143

    dim3 blk(256);
    dim3 blk512(512);

    // 1. x -> bf16 (shared A operand for QKV projection)
    convert_bf16<<<dim3((MROWS_ * DIM_) / 8 / 256), blk, 0, stream>>>(
        x, Xb, (MROWS_ * DIM_) / 8);

    // 2. weight transpose+convert into fused WT: [K,N] fp32 -> [N,K] bf16
    wtrans<<<dim3(DIM_ / 64, DIM_ / 64), blk, 0, stream>>>(Wq, WTq, DIM_, DIM_);
    wtrans<<<dim3(KVD_ / 64, DIM_ / 64), blk, 0, stream>>>(Wk, WTk, DIM_, KVD_);
    wtrans<<<dim3(KVD_ / 64, DIM_ / 64), blk, 0, stream>>>(Wv, WTv, DIM_, KVD_);

    // 3. fused QKV projection: [4096,4096] @ [4096,6144] -> [4096,6144] bf16
    gemm256<__hip_bfloat16><<<dim3(QKVN_ / 256, MROWS_ / 256), blk512, 0, stream>>>(
        Xb, WT, (__hip_bfloat16*)QKV, MROWS_, QKVN_, DIM_);

    // 4. Wo transpose into WT's (now dead) slot
    wtrans<<<dim3(DIM_ / 64, DIM_ / 64), blk, 0, stream>>>(Wo, WoT, DIM_, DIM_);

    // 5. RoPE in-place on fused QKV (Q section then K section)
    {
        int totq = MROWS_ * H_ * 64;
        int totk = MROWS_ * KV_ * 64;
        rope_kernel<<<(totq + 255) / 256, blk, 0, stream>>>(
            QKV, cosb, sinb, H_, 0, totq);
        rope_kernel<<<(totk + 255) / 256, blk, 0, stream>>>(
            QKV, cosb, sinb, KV_, DIM_, totk);
    }

    // 6. MFMA flash attention -> Ab (Xb slot, dead after QKV gemm)
    attn_mfma<<<dim3(8, B_ * H_), blk, 0, stream>>>(
        QKV, (__hip_bfloat16*)Ab);

    // 7. output projection: Ab bf16 @ WoT -> fp32 out
    gemm256<float><<<dim3(DIM_ / 256, MROWS_ / 256), blk512, 0, stream>>>(
        Ab, WoT, out, MROWS_, DIM_, DIM_);
}